// Round 4
// baseline (654.729 us; speedup 1.0000x reference)
//
#include <hip/hip_runtime.h>
#include <hip/hip_bf16.h>
#include <math.h>

#define B 2048
#define L 100
#define D 256

typedef __attribute__((ext_vector_type(8))) short short8;
typedef __attribute__((ext_vector_type(4))) float f32x4;

__device__ __forceinline__ short f2bf(float f) {
    unsigned u = __float_as_uint(f);
    u += 0x7FFFu + ((u >> 16) & 1u);     // RNE
    return (short)(u >> 16);
}
__device__ __forceinline__ float bf2f(short s) {
    return __uint_as_float(((unsigned)(unsigned short)s) << 16);
}
__device__ __forceinline__ void async16(const float* g, float* l) {
    __builtin_amdgcn_global_load_lds(
        (const __attribute__((address_space(1))) unsigned int*)g,
        (__attribute__((address_space(3))) unsigned int*)l, 16, 0, 0);
}
__device__ __forceinline__ float fast_tanh(float x) {
    float cx = fminf(fmaxf(x, -15.f), 15.f);
    float e = __expf(2.f * cx);
    return (e - 1.f) / (e + 1.f);
}

// ---------------------------------------------------------------------------
// K0: abs_w, relw dots + exclusive scan of doc_lens.
// ---------------------------------------------------------------------------
__global__ __launch_bounds__(256) void k0_precompute(
    const float* __restrict__ abs_embed, const float* __restrict__ w_abs,
    const float* __restrict__ rel_embed, const float* __restrict__ w_rel,
    const int* __restrict__ dls,
    float* __restrict__ abs_w, float* __restrict__ relw, int* __restrict__ offs)
{
    int t = threadIdx.x;
    if (t < 100) {
        float s = 0.f;
        for (int j = 0; j < 50; j++) s += abs_embed[t * 50 + j] * w_abs[j];
        abs_w[t] = s;
    }
    if (t < 25) {
        float s = 0.f;
        for (int j = 0; j < 50; j++) s += rel_embed[t * 50 + j] * w_rel[j];
        relw[t] = s;
    }
    __shared__ int lds[256];
    int loc[8];
    int sum = 0;
    for (int k = 0; k < 8; k++) { loc[k] = sum; sum += dls[t * 8 + k]; }
    lds[t] = sum;
    __syncthreads();
    for (int off = 1; off < 256; off <<= 1) {
        int v = (t >= off) ? lds[t - off] : 0;
        __syncthreads();
        lds[t] += v;
        __syncthreads();
    }
    int base = (t > 0) ? lds[t - 1] : 0;
    for (int k = 0; k < 8; k++) offs[t * 8 + k] = base + loc[k];
}

// ---------------------------------------------------------------------------
// KPREP: bf16 hi/lo splits of the three weight matrices, bt-form [N][K].
//   W_nov needs transpose (u = row @ W_nov -> B[n][k] = W_nov[k][n]);
//   fc_w, W_sal are already [out][in].
// ---------------------------------------------------------------------------
__global__ __launch_bounds__(256) void kprep(
    const float* __restrict__ Wnov, const float* __restrict__ fcw,
    const float* __restrict__ Wsal,
    short* __restrict__ Wnh, short* __restrict__ Wnl,
    short* __restrict__ Fh,  short* __restrict__ Fl,
    short* __restrict__ Sh,  short* __restrict__ Sl)
{
    int n = blockIdx.x, k = threadIdx.x;
    {
        float w = Wnov[k * D + n];                 // transpose
        short hi = f2bf(w);
        Wnh[n * D + k] = hi;
        Wnl[n * D + k] = f2bf(w - bf2f(hi));
    }
    {
        float w = fcw[n * D + k];
        short hi = f2bf(w);
        Fh[n * D + k] = hi;
        Fl[n * D + k] = f2bf(w - bf2f(hi));
    }
    {
        float w = Wsal[n * D + k];
        short hi = f2bf(w);
        Sh[n * D + k] = hi;
        Sl[n * D + k] = f2bf(w - bf2f(hi));
    }
}

// ---------------------------------------------------------------------------
// K1: docs[b,:] = mean over valid prefix. 64 float4-lanes x 4 t-ways.
// ---------------------------------------------------------------------------
__global__ __launch_bounds__(256) void k1_docavg(
    const float* __restrict__ sent, const int* __restrict__ dls,
    float* __restrict__ docs)
{
    __shared__ float4 red[4][64];
    int b = blockIdx.x;
    int lane = threadIdx.x & 63, way = threadIdx.x >> 6;
    int dl = dls[b];
    const float4* p = (const float4*)(sent + (size_t)b * L * D) + lane;
    float4 s = make_float4(0.f, 0.f, 0.f, 0.f);
    for (int t = way; t < dl; t += 4) {
        float4 v = p[(size_t)t * (D / 4)];
        s.x += v.x; s.y += v.y; s.z += v.z; s.w += v.w;
    }
    red[way][lane] = s;
    __syncthreads();
    if (way == 0) {
        float4 a = red[0][lane], b1 = red[1][lane],
               c = red[2][lane], d = red[3][lane];
        float inv = 1.f / (float)dl;
        float4 o;
        o.x = (a.x + b1.x + c.x + d.x) * inv;
        o.y = (a.y + b1.y + c.y + d.y) * inv;
        o.z = (a.z + b1.z + c.z + d.z) * inv;
        o.w = (a.w + b1.w + c.w + d.w) * inv;
        ((float4*)(docs + (size_t)b * D))[lane] = o;
    }
}

// ---------------------------------------------------------------------------
// KGEMM<MODE>: Out = A[M x 256] @ B^T (B in bt-form [N=256][K=256], bf16
//   hi/lo split: 3-term MFMA). A staged fp32 via async global_load_lds with
//   global-side XOR swizzle; bf16 split done at fragment-read time.
//   MODE 0: Out=G fp32, store only rows with t<dl.
//   MODE 1: Out = tanh(acc + bv[col])      (doc rep)
//   MODE 2: Out = acc + bv[col]            (uw)
// ---------------------------------------------------------------------------
template <int MODE>
__global__ __launch_bounds__(256) void kgemm(
    const float* __restrict__ A, const short* __restrict__ Bh,
    const short* __restrict__ Bl, const float* __restrict__ bv,
    const int* __restrict__ dls, float* __restrict__ Out)
{
    __shared__ float Ash[128 * 64];      // 32 KB, granule-XOR-swizzled fp32

    int tid = threadIdx.x;
    int lane = tid & 63;
    int wv = tid >> 6;
    int n0 = blockIdx.x * 128;           // gridDim.x = 2 (n fastest -> L2-hot A)
    int m0 = blockIdx.y * 128;
    int m_off = (wv & 1) * 64;
    int n_off = (wv >> 1) * 64;
    int quad = lane >> 4;
    int l15 = lane & 15;

    f32x4 acc[4][4];
#pragma unroll
    for (int fi = 0; fi < 4; fi++)
#pragma unroll
        for (int fj = 0; fj < 4; fj++) acc[fi][fj] = (f32x4){0.f, 0.f, 0.f, 0.f};

    for (int kk = 0; kk < D; kk += 64) {
        // ---- async stage: slot s holds global granule g = (s&15)^(r&15) ----
#pragma unroll
        for (int i = 0; i < 8; i++) {
            int s = (wv * 8 + i) * 64 + lane;
            int r = s >> 4;
            int g = (s & 15) ^ (r & 15);
            async16(A + (size_t)(m0 + r) * D + kk + g * 4,
                    Ash + (size_t)(wv * 8 + i) * 256);
        }
        __syncthreads();

#pragma unroll
        for (int ks = 0; ks < 2; ks++) {
            // B fragments straight from L2-resident splits
            short8 bh[4], bl[4];
#pragma unroll
            for (int fj = 0; fj < 4; fj++) {
                size_t wo = (size_t)(n0 + n_off + fj * 16 + l15) * D
                          + kk + ks * 32 + quad * 8;
                bh[fj] = *(const short8*)(Bh + wo);
                bl[fj] = *(const short8*)(Bl + wo);
            }
#pragma unroll
            for (int fi = 0; fi < 4; fi++) {
                int r = m_off + fi * 16 + l15;
                int g0 = ks * 8 + quad * 2;
                int p0 = r * 16 + ((g0    ) ^ (r & 15));
                int p1 = r * 16 + ((g0 + 1) ^ (r & 15));
                float4 v0 = *(const float4*)&Ash[p0 * 4];
                float4 v1 = *(const float4*)&Ash[p1 * 4];
                float f[8] = {v0.x, v0.y, v0.z, v0.w, v1.x, v1.y, v1.z, v1.w};
                short8 ah, al;
#pragma unroll
                for (int j = 0; j < 8; j++) {
                    unsigned u = __float_as_uint(f[j]);
                    unsigned rr = u + 0x7FFFu + ((u >> 16) & 1u);
                    ah[j] = (short)(rr >> 16);
                    float hf = __uint_as_float(rr & 0xFFFF0000u);
                    al[j] = (short)(__float_as_uint(f[j] - hf) >> 16);
                }
#pragma unroll
                for (int fj = 0; fj < 4; fj++) {
                    acc[fi][fj] = __builtin_amdgcn_mfma_f32_16x16x32_bf16(
                        ah, bh[fj], acc[fi][fj], 0, 0, 0);
                    acc[fi][fj] = __builtin_amdgcn_mfma_f32_16x16x32_bf16(
                        ah, bl[fj], acc[fi][fj], 0, 0, 0);
                    acc[fi][fj] = __builtin_amdgcn_mfma_f32_16x16x32_bf16(
                        al, bh[fj], acc[fi][fj], 0, 0, 0);
                }
            }
        }
        __syncthreads();
    }

    // ---- epilogue (C layout: row=quad*4+q, col=l15; m89-verified) ----
#pragma unroll
    for (int fi = 0; fi < 4; fi++)
#pragma unroll
        for (int q = 0; q < 4; q++) {
            int row = m0 + m_off + fi * 16 + quad * 4 + q;
            bool ok = true;
            if (MODE == 0) {
                unsigned b = __umulhi((unsigned)row, 42949673u);   // row/100
                int t = row - (int)b * 100;
                ok = t < dls[b];
            }
#pragma unroll
            for (int fj = 0; fj < 4; fj++) {
                int col = n0 + n_off + fj * 16 + l15;
                float v = acc[fi][fj][q];
                if (MODE == 1) v = tanhf(v + bv[col]);
                if (MODE == 2) v = v + bv[col];
                if (ok) Out[(size_t)row * D + col] = v;
            }
        }
}

// ---------------------------------------------------------------------------
// K4: recurrence. One wave per doc; lane l owns dims 4l..4l+3 of s.
// ---------------------------------------------------------------------------
__global__ __launch_bounds__(256) void k4_recur(
    const float* __restrict__ sent, const float* __restrict__ G,
    const float* __restrict__ uw, const float* __restrict__ abs_w,
    const float* __restrict__ relw, const float* __restrict__ bias,
    const int* __restrict__ dls, const int* __restrict__ offs,
    float* __restrict__ out)
{
    int wave = threadIdx.x >> 6;
    int lane = threadIdx.x & 63;
    int b = blockIdx.x * 4 + wave;

    int dl = dls[b];
    float dlf = (float)dl;
    int base = offs[b];
    float bs = bias[0];

    const float4* h_ptr = (const float4*)(sent + (size_t)b * L * D) + lane;
    const float4* g_ptr = (const float4*)(G + (size_t)b * L * D) + lane;
    float4 uwv = ((const float4*)(uw + (size_t)b * D))[lane];

    float4 s = make_float4(0.f, 0.f, 0.f, 0.f);
    float4 h = h_ptr[0];
    float4 g = g_ptr[0];

    for (int t = 0; t < dl; t++) {
        float4 hn = h, gn = g;
        if (t + 1 < dl) {   // prefetch (addresses independent of s)
            hn = h_ptr[(size_t)(t + 1) * (D / 4)];
            gn = g_ptr[(size_t)(t + 1) * (D / 4)];
        }
        float4 ts;
        ts.x = fast_tanh(s.x); ts.y = fast_tanh(s.y);
        ts.z = fast_tanh(s.z); ts.w = fast_tanh(s.w);

        float r = h.x * uwv.x + h.y * uwv.y + h.z * uwv.z + h.w * uwv.w
                - (g.x * ts.x + g.y * ts.y + g.z * ts.z + g.w * ts.w);
#pragma unroll
        for (int off = 32; off; off >>= 1) r += __shfl_xor(r, off, 64);

        int idx = (int)rintf((float)(t + 1) * 9.0f / dlf);
        float pre = r + abs_w[t] + relw[idx] + bs;
        float p = 1.0f / (1.0f + __expf(-pre));

        s.x += p * h.x; s.y += p * h.y; s.z += p * h.z; s.w += p * h.w;
        if (lane == 0) out[base + t] = p;
        h = hn; g = gn;
    }
}

// ---------------------------------------------------------------------------
extern "C" void kernel_launch(void* const* d_in, const int* in_sizes, int n_in,
                              void* d_out, int out_size, void* d_ws, size_t ws_size,
                              hipStream_t stream)
{
    const float* sent      = (const float*)d_in[0];
    const float* fc_w      = (const float*)d_in[1];
    const float* fc_b      = (const float*)d_in[2];
    const float* w_content = (const float*)d_in[3];
    const float* W_sal     = (const float*)d_in[4];
    const float* W_nov     = (const float*)d_in[5];
    const float* abs_embed = (const float*)d_in[6];
    const float* rel_embed = (const float*)d_in[7];
    const float* w_abs     = (const float*)d_in[8];
    const float* w_rel     = (const float*)d_in[9];
    const float* bias      = (const float*)d_in[10];
    const int*   dls       = (const int*)d_in[11];
    float* out = (float*)d_out;

    // workspace layout (bytes)
    char* ws = (char*)d_ws;
    size_t o = 0;
    int*   offs  = (int*)(ws + o);   o += 8192;
    float* abs_w = (float*)(ws + o); o += 512;
    float* relw  = (float*)(ws + o); o += 512;
    float* docs  = (float*)(ws + o); o += (size_t)B * D * 4;   // 2 MiB
    float* dtmp  = (float*)(ws + o); o += (size_t)B * D * 4;   // 2 MiB
    float* uw    = (float*)(ws + o); o += (size_t)B * D * 4;   // 2 MiB
    short* Wnh   = (short*)(ws + o); o += (size_t)D * D * 2;
    short* Wnl   = (short*)(ws + o); o += (size_t)D * D * 2;
    short* Fh    = (short*)(ws + o); o += (size_t)D * D * 2;
    short* Fl    = (short*)(ws + o); o += (size_t)D * D * 2;
    short* Sh    = (short*)(ws + o); o += (size_t)D * D * 2;
    short* Sl    = (short*)(ws + o); o += (size_t)D * D * 2;
    o = (o + 255) & ~(size_t)255;
    float* G     = (float*)(ws + o);                           // 200 MiB

    hipLaunchKernelGGL(k0_precompute, dim3(1), dim3(256), 0, stream,
                       abs_embed, w_abs, rel_embed, w_rel, dls, abs_w, relw, offs);
    hipLaunchKernelGGL(kprep, dim3(D), dim3(D), 0, stream,
                       W_nov, fc_w, W_sal, Wnh, Wnl, Fh, Fl, Sh, Sl);
    hipLaunchKernelGGL(k1_docavg, dim3(B), dim3(256), 0, stream, sent, dls, docs);
    hipLaunchKernelGGL(kgemm<1>, dim3(2, B / 128), dim3(256), 0, stream,
                       docs, Fh, Fl, fc_b, (const int*)nullptr, dtmp);
    hipLaunchKernelGGL(kgemm<2>, dim3(2, B / 128), dim3(256), 0, stream,
                       dtmp, Sh, Sl, w_content, (const int*)nullptr, uw);
    hipLaunchKernelGGL(kgemm<0>, dim3(2, (B * L) / 128), dim3(256), 0, stream,
                       sent, Wnh, Wnl, (const float*)nullptr, dls, G);
    hipLaunchKernelGGL(k4_recur, dim3(B / 4), dim3(256), 0, stream,
                       sent, G, uw, abs_w, relw, bias, dls, offs, out);
}